// Round 1
// baseline (3191.080 us; speedup 1.0000x reference)
//
#include <hip/hip_runtime.h>

#define D_MODEL 1024
#define NH 16
#define HD 64
#define KRET 32
#define BANK 131072
#define BB 8
#define TT 2048
#define MTOK 16384
#define EPSN 1e-12f

typedef __attribute__((ext_vector_type(8))) short bf16x8;
typedef __attribute__((ext_vector_type(4))) float f32x4;

__device__ __forceinline__ unsigned short f2bf(float f) {
  unsigned int u = __float_as_uint(f);
  u += 0x7fffu + ((u >> 16) & 1u);
  return (unsigned short)(u >> 16);
}
__device__ __forceinline__ float bf2f(unsigned short h) {
  return __uint_as_float(((unsigned int)h) << 16);
}

__device__ __forceinline__ void gload16(const void* g, void* l) {
  __builtin_amdgcn_global_load_lds(
      (const __attribute__((address_space(1))) unsigned int*)g,
      (__attribute__((address_space(3))) unsigned int*)l, 16, 0, 0);
}

// ---------------- conversion: f32 -> bf16, 4 elems/thread ----------------
__global__ __launch_bounds__(256) void k_conv_bf16(const float* __restrict__ in,
                                                   unsigned short* __restrict__ out, int n4) {
  int i = blockIdx.x * 256 + threadIdx.x;
  if (i >= n4) return;
  float4 v = ((const float4*)in)[i];
  ushort4 o;
  o.x = f2bf(v.x); o.y = f2bf(v.y); o.z = f2bf(v.z); o.w = f2bf(v.w);
  ((ushort4*)out)[i] = o;
}

// ---------------- weight transpose + bf16: WT[n][k] = bf16(W[k][n]) ----------------
__global__ __launch_bounds__(256) void k_transW(const float* W0, const float* W1,
                                                const float* W2, const float* W3,
                                                unsigned short* T0, unsigned short* T1,
                                                unsigned short* T2, unsigned short* T3) {
  const float* W; unsigned short* T;
  switch (blockIdx.z) {
    case 0: W = W0; T = T0; break;
    case 1: W = W1; T = T1; break;
    case 2: W = W2; T = T2; break;
    default: W = W3; T = T3; break;
  }
  __shared__ float tile[64][65];
  int k0 = blockIdx.y * 64, n0 = blockIdx.x * 64;
  int tid = threadIdx.x;
#pragma unroll
  for (int i = 0; i < 16; i++) {
    int idx = tid + i * 256; int r = idx >> 6, c = idx & 63;
    tile[r][c] = W[(size_t)(k0 + r) * D_MODEL + n0 + c];
  }
  __syncthreads();
#pragma unroll
  for (int i = 0; i < 16; i++) {
    int idx = tid + i * 256; int r = idx >> 6, c = idx & 63;
    T[(size_t)(n0 + r) * D_MODEL + k0 + c] = f2bf(tile[c][r]);
  }
}

// ---------------- mean over T (stage 1: partial sums over 256 t's) ----------------
__global__ __launch_bounds__(256) void k_meanpart(const float* __restrict__ x,
                                                  float* __restrict__ part) {
  int b = blockIdx.z, tc = blockIdx.y;
  int d = blockIdx.x * 256 + threadIdx.x;
  const float* xp = x + ((size_t)b * TT + tc * 256) * D_MODEL + d;
  float s = 0.f;
  for (int t = 0; t < 256; t++) s += xp[(size_t)t * D_MODEL];
  part[((size_t)b * 8 + tc) * D_MODEL + d] = s;
}

// ---------------- finish mean + normalize q ----------------
__global__ __launch_bounds__(256) void k_qnorm(const float* __restrict__ part,
                                               float* __restrict__ qn) {
  int b = blockIdx.x; int tid = threadIdx.x;
  __shared__ float qs[D_MODEL];
  __shared__ float red[4];
  float ss = 0.f;
#pragma unroll
  for (int c = 0; c < 4; c++) {
    int d = c * 256 + tid;
    float s = 0.f;
#pragma unroll
    for (int p = 0; p < 8; p++) s += part[((size_t)b * 8 + p) * D_MODEL + d];
    s *= (1.f / TT);
    qs[d] = s; ss += s * s;
  }
#pragma unroll
  for (int m = 32; m >= 1; m >>= 1) ss += __shfl_xor(ss, m);
  if ((tid & 63) == 0) red[tid >> 6] = ss;
  __syncthreads();
  float tot = red[0] + red[1] + red[2] + red[3];
  float inv = 1.f / fmaxf(sqrtf(tot), EPSN);
#pragma unroll
  for (int c = 0; c < 4; c++) {
    int d = c * 256 + tid;
    qn[(size_t)b * D_MODEL + d] = qs[d] * inv;
  }
}

// ---------------- cosine sims: one wave per 4 key rows ----------------
__global__ __launch_bounds__(256) void k_sims(const float* __restrict__ mk,
                                              const float* __restrict__ qn,
                                              float* __restrict__ sims) {
  int wave = threadIdx.x >> 6, lane = threadIdx.x & 63;
  int row0 = (blockIdx.x * 4 + wave) * 4;
  float4 kv[4][4];
#pragma unroll
  for (int r = 0; r < 4; r++) {
    const float4* kr = (const float4*)(mk + (size_t)(row0 + r) * D_MODEL);
#pragma unroll
    for (int i = 0; i < 4; i++) kv[r][i] = kr[lane + 64 * i];
  }
  float ss[4] = {0.f, 0.f, 0.f, 0.f};
#pragma unroll
  for (int r = 0; r < 4; r++)
#pragma unroll
    for (int i = 0; i < 4; i++)
      ss[r] += kv[r][i].x * kv[r][i].x + kv[r][i].y * kv[r][i].y +
               kv[r][i].z * kv[r][i].z + kv[r][i].w * kv[r][i].w;
  float dots[8][4];
#pragma unroll
  for (int b = 0; b < 8; b++)
#pragma unroll
    for (int r = 0; r < 4; r++) dots[b][r] = 0.f;
#pragma unroll
  for (int b = 0; b < 8; b++) {
    const float4* qb = (const float4*)(qn + (size_t)b * D_MODEL);
#pragma unroll
    for (int i = 0; i < 4; i++) {
      float4 q4 = qb[lane + 64 * i];
#pragma unroll
      for (int r = 0; r < 4; r++)
        dots[b][r] += kv[r][i].x * q4.x + kv[r][i].y * q4.y +
                      kv[r][i].z * q4.z + kv[r][i].w * q4.w;
    }
  }
#pragma unroll
  for (int m = 32; m >= 1; m >>= 1) {
#pragma unroll
    for (int r = 0; r < 4; r++) ss[r] += __shfl_xor(ss[r], m);
#pragma unroll
    for (int b = 0; b < 8; b++)
#pragma unroll
      for (int r = 0; r < 4; r++) dots[b][r] += __shfl_xor(dots[b][r], m);
  }
  if (lane == 0) {
#pragma unroll
    for (int r = 0; r < 4; r++) {
      float inv = 1.f / fmaxf(sqrtf(ss[r]), EPSN);
#pragma unroll
      for (int b = 0; b < 8; b++)
        sims[(size_t)b * BANK + row0 + r] = dots[b][r] * inv;
    }
  }
}

// ---------------- exact top-32 via iterative argmax (destroys sims) ----------------
__global__ __launch_bounds__(256) void k_topk(float* __restrict__ sims, int* __restrict__ idx) {
  int b = blockIdx.x; int tid = threadIdx.x;
  int wave = tid >> 6, lane = tid & 63;
  __shared__ float wv[4];
  __shared__ int wi[4];
  float* sb = sims + (size_t)b * BANK;
  for (int it = 0; it < KRET; ++it) {
    float best = -1e30f; int bi = BANK;
    for (int i = tid; i < BANK; i += 256) {
      float v = sb[i];
      if (v > best || (v == best && i < bi)) { best = v; bi = i; }
    }
#pragma unroll
    for (int m = 32; m >= 1; m >>= 1) {
      float ov = __shfl_xor(best, m);
      int oi = __shfl_xor(bi, m);
      if (ov > best || (ov == best && oi < bi)) { best = ov; bi = oi; }
    }
    if (lane == 0) { wv[wave] = best; wi[wave] = bi; }
    __syncthreads();
    if (tid == 0) {
      float fb = wv[0]; int fi = wi[0];
      for (int w = 1; w < 4; w++)
        if (wv[w] > fb || (wv[w] == fb && wi[w] < fi)) { fb = wv[w]; fi = wi[w]; }
      idx[b * KRET + it] = fi;
      sb[fi] = -1e30f;
    }
    __syncthreads();
  }
}

// ---------------- gather retrieved rows -> bf16 ----------------
__global__ __launch_bounds__(256) void k_gather(const float* __restrict__ mv,
                                                const int* __restrict__ idx,
                                                unsigned short* __restrict__ retr) {
  int row = blockIdx.x;
  int src = idx[row];
  float4 v = ((const float4*)(mv + (size_t)src * D_MODEL))[threadIdx.x];
  ushort4 o;
  o.x = f2bf(v.x); o.y = f2bf(v.y); o.z = f2bf(v.z); o.w = f2bf(v.w);
  ((ushort4*)(retr + (size_t)row * D_MODEL))[threadIdx.x] = o;
}

// ---------------- bf16 MFMA GEMM, 128x128 tile, BK=32 (m97 structure) ----------------
// A: (M,1024) bf16 row-major. Bt: (N,1024) bf16 row-major (= B^T).
// MODE 0: Q-proj -> out_b bf16 in (B,H,T,hd)
// MODE 1: KV-proj (N=2048) -> out_f = K (B,H,k,hd) f32, out_f2 = V
// MODE 2: O-proj -> out_f = xres + gate * acc (f32)
template <int MODE>
__global__ __launch_bounds__(256) void k_gemm(const unsigned short* __restrict__ A,
                                              const unsigned short* __restrict__ Bt,
                                              float* __restrict__ out_f,
                                              unsigned short* __restrict__ out_b,
                                              float* __restrict__ out_f2,
                                              const float* __restrict__ xres,
                                              const float* __restrict__ gatep) {
  __shared__ __align__(16) unsigned short As[128 * 32];
  __shared__ __align__(16) unsigned short Bs[128 * 32];
  const int tid = threadIdx.x;
  const int wave = tid >> 6, lane = tid & 63;
  const int bm = blockIdx.x * 128, bn = blockIdx.y * 128;
  const int wm = (wave >> 1) * 64, wn = (wave & 1) * 64;
  const int frow = lane & 15, kg = lane >> 4;
  const int K = 1024;

  f32x4 acc[4][4] = {};

  const int g0 = tid * 8;
  const int g1 = 2048 + tid * 8;
  const unsigned short* a0 = A + (size_t)(bm + (g0 >> 5)) * K + (g0 & 31);
  const unsigned short* a1 = A + (size_t)(bm + (g1 >> 5)) * K + (g1 & 31);
  const unsigned short* b0 = Bt + (size_t)(bn + (g0 >> 5)) * K + (g0 & 31);
  const unsigned short* b1 = Bt + (size_t)(bn + (g1 >> 5)) * K + (g1 & 31);
  unsigned short* lA0 = &As[wave * 512];
  unsigned short* lA1 = &As[2048 + wave * 512];
  unsigned short* lB0 = &Bs[wave * 512];
  unsigned short* lB1 = &Bs[2048 + wave * 512];

  for (int k0 = 0; k0 < K; k0 += 32) {
    gload16(a0 + k0, lA0);
    gload16(a1 + k0, lA1);
    gload16(b0 + k0, lB0);
    gload16(b1 + k0, lB1);
    __syncthreads();
    bf16x8 fa[4], fb[4];
#pragma unroll
    for (int i = 0; i < 4; i++)
      fa[i] = *(const bf16x8*)&As[(wm + i * 16 + frow) * 32 + kg * 8];
#pragma unroll
    for (int i = 0; i < 4; i++)
      fb[i] = *(const bf16x8*)&Bs[(wn + i * 16 + frow) * 32 + kg * 8];
#pragma unroll
    for (int i = 0; i < 4; i++)
#pragma unroll
      for (int j = 0; j < 4; j++)
        acc[i][j] = __builtin_amdgcn_mfma_f32_16x16x32_bf16(fa[i], fb[j], acc[i][j], 0, 0, 0);
    __syncthreads();
  }

  const int crow = (lane >> 4) * 4, ccol = lane & 15;
  if (MODE == 2) {
    float gate = 1.f / (1.f + __expf(-gatep[0]));
#pragma unroll
    for (int i = 0; i < 4; i++)
#pragma unroll
      for (int j = 0; j < 4; j++)
#pragma unroll
        for (int r = 0; r < 4; r++) {
          int gm = bm + wm + i * 16 + crow + r;
          int gn = bn + wn + j * 16 + ccol;
          size_t off = (size_t)gm * D_MODEL + gn;
          out_f[off] = xres[off] + gate * acc[i][j][r];
        }
  } else if (MODE == 0) {
#pragma unroll
    for (int i = 0; i < 4; i++)
#pragma unroll
      for (int j = 0; j < 4; j++)
#pragma unroll
        for (int r = 0; r < 4; r++) {
          int gm = bm + wm + i * 16 + crow + r;
          int gn = bn + wn + j * 16 + ccol;
          int b = gm >> 11, t = gm & 2047, h = gn >> 6, d = gn & 63;
          out_b[((((size_t)b * NH + h) * TT + t) << 6) + d] = f2bf(acc[i][j][r]);
        }
  } else {
#pragma unroll
    for (int i = 0; i < 4; i++)
#pragma unroll
      for (int j = 0; j < 4; j++)
#pragma unroll
        for (int r = 0; r < 4; r++) {
          int gm = bm + wm + i * 16 + crow + r;
          int gn = bn + wn + j * 16 + ccol;
          int b = gm >> 5, jj = gm & 31;
          if (gn < 1024) {
            int h = gn >> 6, d = gn & 63;
            out_f[((((size_t)b * NH + h) * KRET + jj) << 6) + d] = acc[i][j][r];
          } else {
            int gn2 = gn - 1024;
            int h = gn2 >> 6, d = gn2 & 63;
            out_f2[((((size_t)b * NH + h) * KRET + jj) << 6) + d] = acc[i][j][r];
          }
        }
  }
}

// ---------------- cross-attention over k=32 retrieved docs ----------------
__global__ __launch_bounds__(256) void k_attn(const unsigned short* __restrict__ Qb,
                                              const float* __restrict__ Kws,
                                              const float* __restrict__ Vws,
                                              unsigned short* __restrict__ ctx) {
  __shared__ __align__(16) float Ks[KRET * HD];
  __shared__ __align__(16) float Vs[KRET * HD];
  int bh = blockIdx.y; int b = bh >> 4, h = bh & 15;
  int tid = threadIdx.x;
  int t = blockIdx.x * 256 + tid;
  const float4* kp = (const float4*)(Kws + (size_t)bh * KRET * HD);
  const float4* vp = (const float4*)(Vws + (size_t)bh * KRET * HD);
  ((float4*)Ks)[tid] = kp[tid];
  ((float4*)Ks)[tid + 256] = kp[tid + 256];
  ((float4*)Vs)[tid] = vp[tid];
  ((float4*)Vs)[tid + 256] = vp[tid + 256];
  __syncthreads();

  const uint4* qp = (const uint4*)(Qb + ((size_t)bh * TT + t) * HD);
  float q[64];
#pragma unroll
  for (int i = 0; i < 8; i++) {
    uint4 u = qp[i];
    unsigned vals[4] = {u.x, u.y, u.z, u.w};
#pragma unroll
    for (int w = 0; w < 4; w++) {
      q[i * 8 + w * 2 + 0] = bf2f((unsigned short)(vals[w] & 0xffffu));
      q[i * 8 + w * 2 + 1] = bf2f((unsigned short)(vals[w] >> 16));
    }
  }
  float s[KRET];
#pragma unroll
  for (int j = 0; j < KRET; j++) {
    const float4* kr = (const float4*)&Ks[j * HD];
    float a = 0.f;
#pragma unroll
    for (int d4 = 0; d4 < 16; d4++) {
      float4 kk = kr[d4];
      a += q[d4 * 4 + 0] * kk.x + q[d4 * 4 + 1] * kk.y +
           q[d4 * 4 + 2] * kk.z + q[d4 * 4 + 3] * kk.w;
    }
    s[j] = a * 0.125f;
  }
  float m = s[0];
#pragma unroll
  for (int j = 1; j < KRET; j++) m = fmaxf(m, s[j]);
  float sum = 0.f;
#pragma unroll
  for (int j = 0; j < KRET; j++) { s[j] = __expf(s[j] - m); sum += s[j]; }
  float inv = 1.f / sum;
  float o[64];
#pragma unroll
  for (int d = 0; d < 64; d++) o[d] = 0.f;
#pragma unroll
  for (int j = 0; j < KRET; j++) {
    float p = s[j] * inv;
    const float4* vr = (const float4*)&Vs[j * HD];
#pragma unroll
    for (int d4 = 0; d4 < 16; d4++) {
      float4 vv = vr[d4];
      o[d4 * 4 + 0] += p * vv.x; o[d4 * 4 + 1] += p * vv.y;
      o[d4 * 4 + 2] += p * vv.z; o[d4 * 4 + 3] += p * vv.w;
    }
  }
  unsigned short* cp = ctx + ((size_t)(b * TT + t)) * D_MODEL + h * HD;
#pragma unroll
  for (int d4 = 0; d4 < 16; d4++) {
    ushort4 w4;
    w4.x = f2bf(o[d4 * 4 + 0]); w4.y = f2bf(o[d4 * 4 + 1]);
    w4.z = f2bf(o[d4 * 4 + 2]); w4.w = f2bf(o[d4 * 4 + 3]);
    ((ushort4*)cp)[d4] = w4;
  }
}

extern "C" void kernel_launch(void* const* d_in, const int* in_sizes, int n_in,
                              void* d_out, int out_size, void* d_ws, size_t ws_size,
                              hipStream_t stream) {
  const float* x = (const float*)d_in[0];
  const float* mk = (const float*)d_in[1];
  const float* mv = (const float*)d_in[2];
  const float* Wq = (const float*)d_in[3];
  const float* Wk = (const float*)d_in[4];
  const float* Wv = (const float*)d_in[5];
  const float* Wo = (const float*)d_in[6];
  const float* gatep = (const float*)d_in[7];
  float* out = (float*)d_out;

  char* ws = (char*)d_ws;
  unsigned short* xb   = (unsigned short*)(ws);               // 32MB x bf16; reused as ctx bf16
  unsigned short* Qb   = (unsigned short*)(ws + 33554432);    // 32MB Q bf16 (B,H,T,hd)
  unsigned short* WqT  = (unsigned short*)(ws + 67108864);    // 2MB
  unsigned short* WkvT = (unsigned short*)(ws + 69206016);    // 4MB (Wk^T then Wv^T)
  unsigned short* WoT  = (unsigned short*)(ws + 73400320);    // 2MB
  float* qpart = (float*)(ws + 75497472);                     // 256KB
  float* qn    = (float*)(ws + 75759616);                     // 32KB
  float* sims  = (float*)(ws + 75792384);                     // 4MB
  int*   idx   = (int*)(ws + 79986688);                       // 1KB
  unsigned short* retr = (unsigned short*)(ws + 79987712);    // 512KB
  float* Kws   = (float*)(ws + 80512000);                     // 1MB (B,H,k,hd)
  float* Vws   = (float*)(ws + 81560576);                     // 1MB

  // 1. x -> bf16
  k_conv_bf16<<<dim3(16384), 256, 0, stream>>>(x, xb, MTOK * D_MODEL / 4);
  // 2. weight transposes -> bf16 B^T layouts
  k_transW<<<dim3(16, 16, 4), 256, 0, stream>>>(Wq, Wk, Wv, Wo,
                                                WqT, WkvT, WkvT + 1048576, WoT);
  // 3-4. mean-pool q then normalize
  k_meanpart<<<dim3(4, 8, 8), 256, 0, stream>>>(x, qpart);
  k_qnorm<<<dim3(8), 256, 0, stream>>>(qpart, qn);
  // 5. cosine sims vs key bank
  k_sims<<<dim3(BANK / 16), 256, 0, stream>>>(mk, qn, sims);
  // 6. exact top-32 per batch
  k_topk<<<dim3(8), 256, 0, stream>>>(sims, idx);
  // 7. gather retrieved values -> bf16
  k_gather<<<dim3(256), 256, 0, stream>>>(mv, idx, retr);
  // 8. Q = x @ Wq  (writes (B,H,T,hd) bf16)
  k_gemm<0><<<dim3(128, 8), 256, 0, stream>>>(xb, WqT, nullptr, Qb, nullptr, nullptr, nullptr);
  // 9. K,V = retrieved @ [Wk;Wv]
  k_gemm<1><<<dim3(2, 16), 256, 0, stream>>>(retr, WkvT, Kws, nullptr, Vws, nullptr, nullptr);
  // 10. attention -> ctx bf16 (reuses xb)
  k_attn<<<dim3(8, 128), 256, 0, stream>>>(Qb, Kws, Vws, xb);
  // 11. out = x + sigmoid(gate) * ctx @ Wo
  k_gemm<2><<<dim3(128, 8), 256, 0, stream>>>(xb, WoT, out, nullptr, nullptr, x, gatep);
}

// Round 2
// 502.006 us; speedup vs baseline: 6.3567x; 6.3567x over previous
//
#include <hip/hip_runtime.h>

#define D_MODEL 1024
#define NH 16
#define HD 64
#define KRET 32
#define BANK 131072
#define BB 8
#define TT 2048
#define MTOK 16384
#define EPSN 1e-12f

typedef __attribute__((ext_vector_type(8))) short bf16x8;
typedef __attribute__((ext_vector_type(4))) float f32x4;

__device__ __forceinline__ unsigned short f2bf(float f) {
  unsigned int u = __float_as_uint(f);
  u += 0x7fffu + ((u >> 16) & 1u);
  return (unsigned short)(u >> 16);
}
__device__ __forceinline__ float bf2f(unsigned short h) {
  return __uint_as_float(((unsigned int)h) << 16);
}

__device__ __forceinline__ void gload16(const void* g, void* l) {
  __builtin_amdgcn_global_load_lds(
      (const __attribute__((address_space(1))) unsigned int*)g,
      (__attribute__((address_space(3))) unsigned int*)l, 16, 0, 0);
}

// ---------------- conversion: f32 -> bf16, 4 elems/thread ----------------
__global__ __launch_bounds__(256) void k_conv_bf16(const float* __restrict__ in,
                                                   unsigned short* __restrict__ out, int n4) {
  int i = blockIdx.x * 256 + threadIdx.x;
  if (i >= n4) return;
  float4 v = ((const float4*)in)[i];
  ushort4 o;
  o.x = f2bf(v.x); o.y = f2bf(v.y); o.z = f2bf(v.z); o.w = f2bf(v.w);
  ((ushort4*)out)[i] = o;
}

// ---------------- weight transpose + bf16: WT[n][k] = bf16(W[k][n]) ----------------
__global__ __launch_bounds__(256) void k_transW(const float* W0, const float* W1,
                                                const float* W2, const float* W3,
                                                unsigned short* T0, unsigned short* T1,
                                                unsigned short* T2, unsigned short* T3) {
  const float* W; unsigned short* T;
  switch (blockIdx.z) {
    case 0: W = W0; T = T0; break;
    case 1: W = W1; T = T1; break;
    case 2: W = W2; T = T2; break;
    default: W = W3; T = T3; break;
  }
  __shared__ float tile[64][65];
  int k0 = blockIdx.y * 64, n0 = blockIdx.x * 64;
  int tid = threadIdx.x;
#pragma unroll
  for (int i = 0; i < 16; i++) {
    int idx = tid + i * 256; int r = idx >> 6, c = idx & 63;
    tile[r][c] = W[(size_t)(k0 + r) * D_MODEL + n0 + c];
  }
  __syncthreads();
#pragma unroll
  for (int i = 0; i < 16; i++) {
    int idx = tid + i * 256; int r = idx >> 6, c = idx & 63;
    T[(size_t)(n0 + r) * D_MODEL + k0 + c] = f2bf(tile[c][r]);
  }
}

// ---------------- mean over T (stage 1: partial sums over 256 t's) ----------------
__global__ __launch_bounds__(256) void k_meanpart(const float* __restrict__ x,
                                                  float* __restrict__ part) {
  int b = blockIdx.z, tc = blockIdx.y;
  int d = blockIdx.x * 256 + threadIdx.x;
  const float* xp = x + ((size_t)b * TT + tc * 256) * D_MODEL + d;
  float s = 0.f;
  for (int t = 0; t < 256; t++) s += xp[(size_t)t * D_MODEL];
  part[((size_t)b * 8 + tc) * D_MODEL + d] = s;
}

// ---------------- finish mean + normalize q ----------------
__global__ __launch_bounds__(256) void k_qnorm(const float* __restrict__ part,
                                               float* __restrict__ qn) {
  int b = blockIdx.x; int tid = threadIdx.x;
  __shared__ float qs[D_MODEL];
  __shared__ float red[4];
  float ss = 0.f;
#pragma unroll
  for (int c = 0; c < 4; c++) {
    int d = c * 256 + tid;
    float s = 0.f;
#pragma unroll
    for (int p = 0; p < 8; p++) s += part[((size_t)b * 8 + p) * D_MODEL + d];
    s *= (1.f / TT);
    qs[d] = s; ss += s * s;
  }
#pragma unroll
  for (int m = 32; m >= 1; m >>= 1) ss += __shfl_xor(ss, m);
  if ((tid & 63) == 0) red[tid >> 6] = ss;
  __syncthreads();
  float tot = red[0] + red[1] + red[2] + red[3];
  float inv = 1.f / fmaxf(sqrtf(tot), EPSN);
#pragma unroll
  for (int c = 0; c < 4; c++) {
    int d = c * 256 + tid;
    qn[(size_t)b * D_MODEL + d] = qs[d] * inv;
  }
}

// ---------------- cosine sims: one wave per 4 key rows ----------------
__global__ __launch_bounds__(256) void k_sims(const float* __restrict__ mk,
                                              const float* __restrict__ qn,
                                              float* __restrict__ sims) {
  int wave = threadIdx.x >> 6, lane = threadIdx.x & 63;
  int row0 = (blockIdx.x * 4 + wave) * 4;
  float4 kv[4][4];
#pragma unroll
  for (int r = 0; r < 4; r++) {
    const float4* kr = (const float4*)(mk + (size_t)(row0 + r) * D_MODEL);
#pragma unroll
    for (int i = 0; i < 4; i++) kv[r][i] = kr[lane + 64 * i];
  }
  float ss[4] = {0.f, 0.f, 0.f, 0.f};
#pragma unroll
  for (int r = 0; r < 4; r++)
#pragma unroll
    for (int i = 0; i < 4; i++)
      ss[r] += kv[r][i].x * kv[r][i].x + kv[r][i].y * kv[r][i].y +
               kv[r][i].z * kv[r][i].z + kv[r][i].w * kv[r][i].w;
  float dots[8][4];
#pragma unroll
  for (int b = 0; b < 8; b++)
#pragma unroll
    for (int r = 0; r < 4; r++) dots[b][r] = 0.f;
#pragma unroll
  for (int b = 0; b < 8; b++) {
    const float4* qb = (const float4*)(qn + (size_t)b * D_MODEL);
#pragma unroll
    for (int i = 0; i < 4; i++) {
      float4 q4 = qb[lane + 64 * i];
#pragma unroll
      for (int r = 0; r < 4; r++)
        dots[b][r] += kv[r][i].x * q4.x + kv[r][i].y * q4.y +
                      kv[r][i].z * q4.z + kv[r][i].w * q4.w;
    }
  }
#pragma unroll
  for (int m = 32; m >= 1; m >>= 1) {
#pragma unroll
    for (int r = 0; r < 4; r++) ss[r] += __shfl_xor(ss[r], m);
#pragma unroll
    for (int b = 0; b < 8; b++)
#pragma unroll
      for (int r = 0; r < 4; r++) dots[b][r] += __shfl_xor(dots[b][r], m);
  }
  if (lane == 0) {
#pragma unroll
    for (int r = 0; r < 4; r++) {
      float inv = 1.f / fmaxf(sqrtf(ss[r]), EPSN);
#pragma unroll
      for (int b = 0; b < 8; b++)
        sims[(size_t)b * BANK + row0 + r] = dots[b][r] * inv;
    }
  }
}

// ---------------- two-stage exact top-32 ----------------
// Stage A: per (batch, chunk of 2048) local top-32 by (value desc, index asc).
__global__ __launch_bounds__(256) void k_topk_local(const float* __restrict__ sims,
                                                    float* __restrict__ cval,
                                                    int* __restrict__ cidx) {
  int b = blockIdx.y, chunk = blockIdx.x;
  int tid = threadIdx.x, wave = tid >> 6, lane = tid & 63;
  const float* sb = sims + (size_t)b * BANK + chunk * 2048;
  float v[8]; int gi[8];
#pragma unroll
  for (int j = 0; j < 8; j++) {
    int loc = j * 256 + tid;
    v[j] = sb[loc];
    gi[j] = chunk * 2048 + loc;
  }
  __shared__ float wv[4]; __shared__ int wi[4];
  __shared__ int bcast;
  for (int it = 0; it < KRET; ++it) {
    float best = -1e30f; int besti = 1 << 30;
#pragma unroll
    for (int j = 0; j < 8; j++)
      if (v[j] > best || (v[j] == best && gi[j] < besti)) { best = v[j]; besti = gi[j]; }
#pragma unroll
    for (int m = 32; m >= 1; m >>= 1) {
      float ov = __shfl_xor(best, m); int oi = __shfl_xor(besti, m);
      if (ov > best || (ov == best && oi < besti)) { best = ov; besti = oi; }
    }
    if (lane == 0) { wv[wave] = best; wi[wave] = besti; }
    __syncthreads();
    if (tid == 0) {
      float fb = wv[0]; int fi = wi[0];
      for (int w = 1; w < 4; w++)
        if (wv[w] > fb || (wv[w] == fb && wi[w] < fi)) { fb = wv[w]; fi = wi[w]; }
      bcast = fi;
      cval[((size_t)b * 64 + chunk) * KRET + it] = fb;
      cidx[((size_t)b * 64 + chunk) * KRET + it] = fi;
    }
    __syncthreads();
    int w = bcast;
#pragma unroll
    for (int j = 0; j < 8; j++)
      if (gi[j] == w) v[j] = -1e30f;
  }
}

// Stage B: merge 64*32=2048 candidates per batch -> final 32 indices.
__global__ __launch_bounds__(256) void k_topk_merge(const float* __restrict__ cval,
                                                    const int* __restrict__ cidx,
                                                    int* __restrict__ idx) {
  int b = blockIdx.x;
  int tid = threadIdx.x, wave = tid >> 6, lane = tid & 63;
  const float* cv = cval + (size_t)b * 2048;
  const int* ci = cidx + (size_t)b * 2048;
  float v[8]; int gi[8];
#pragma unroll
  for (int j = 0; j < 8; j++) {
    int loc = j * 256 + tid;
    v[j] = cv[loc];
    gi[j] = ci[loc];
  }
  __shared__ float wv[4]; __shared__ int wi[4];
  __shared__ int bcast;
  for (int it = 0; it < KRET; ++it) {
    float best = -1e30f; int besti = 1 << 30;
#pragma unroll
    for (int j = 0; j < 8; j++)
      if (v[j] > best || (v[j] == best && gi[j] < besti)) { best = v[j]; besti = gi[j]; }
#pragma unroll
    for (int m = 32; m >= 1; m >>= 1) {
      float ov = __shfl_xor(best, m); int oi = __shfl_xor(besti, m);
      if (ov > best || (ov == best && oi < besti)) { best = ov; besti = oi; }
    }
    if (lane == 0) { wv[wave] = best; wi[wave] = besti; }
    __syncthreads();
    if (tid == 0) {
      float fb = wv[0]; int fi = wi[0];
      for (int w = 1; w < 4; w++)
        if (wv[w] > fb || (wv[w] == fb && wi[w] < fi)) { fb = wv[w]; fi = wi[w]; }
      bcast = fi;
      idx[b * KRET + it] = fi;
    }
    __syncthreads();
    int w = bcast;
#pragma unroll
    for (int j = 0; j < 8; j++)
      if (gi[j] == w) v[j] = -1e30f;
  }
}

// ---------------- gather retrieved rows -> bf16 ----------------
__global__ __launch_bounds__(256) void k_gather(const float* __restrict__ mv,
                                                const int* __restrict__ idx,
                                                unsigned short* __restrict__ retr) {
  int row = blockIdx.x;
  int src = idx[row];
  float4 v = ((const float4*)(mv + (size_t)src * D_MODEL))[threadIdx.x];
  ushort4 o;
  o.x = f2bf(v.x); o.y = f2bf(v.y); o.z = f2bf(v.z); o.w = f2bf(v.w);
  ((ushort4*)(retr + (size_t)row * D_MODEL))[threadIdx.x] = o;
}

// ---------------- bf16 MFMA GEMM, 128x128 tile, BK=32 (m97 structure) ----------------
// A: (M,1024) bf16 row-major. Bt: (N,1024) bf16 row-major (= B^T).
// MODE 0: Q-proj -> out_b bf16 in (B,H,T,hd)
// MODE 1: KV-proj (N=2048) -> out_f = K (B,H,k,hd) f32, out_f2 = V
// MODE 2: O-proj -> out_f = xres + gate * acc (f32)
template <int MODE>
__global__ __launch_bounds__(256) void k_gemm(const unsigned short* __restrict__ A,
                                              const unsigned short* __restrict__ Bt,
                                              float* __restrict__ out_f,
                                              unsigned short* __restrict__ out_b,
                                              float* __restrict__ out_f2,
                                              const float* __restrict__ xres,
                                              const float* __restrict__ gatep) {
  __shared__ __align__(16) unsigned short As[128 * 32];
  __shared__ __align__(16) unsigned short Bs[128 * 32];
  const int tid = threadIdx.x;
  const int wave = tid >> 6, lane = tid & 63;
  const int bm = blockIdx.x * 128, bn = blockIdx.y * 128;
  const int wm = (wave >> 1) * 64, wn = (wave & 1) * 64;
  const int frow = lane & 15, kg = lane >> 4;
  const int K = 1024;

  f32x4 acc[4][4] = {};

  const int g0 = tid * 8;
  const int g1 = 2048 + tid * 8;
  const unsigned short* a0 = A + (size_t)(bm + (g0 >> 5)) * K + (g0 & 31);
  const unsigned short* a1 = A + (size_t)(bm + (g1 >> 5)) * K + (g1 & 31);
  const unsigned short* b0 = Bt + (size_t)(bn + (g0 >> 5)) * K + (g0 & 31);
  const unsigned short* b1 = Bt + (size_t)(bn + (g1 >> 5)) * K + (g1 & 31);
  unsigned short* lA0 = &As[wave * 512];
  unsigned short* lA1 = &As[2048 + wave * 512];
  unsigned short* lB0 = &Bs[wave * 512];
  unsigned short* lB1 = &Bs[2048 + wave * 512];

  for (int k0 = 0; k0 < K; k0 += 32) {
    gload16(a0 + k0, lA0);
    gload16(a1 + k0, lA1);
    gload16(b0 + k0, lB0);
    gload16(b1 + k0, lB1);
    __syncthreads();
    bf16x8 fa[4], fb[4];
#pragma unroll
    for (int i = 0; i < 4; i++)
      fa[i] = *(const bf16x8*)&As[(wm + i * 16 + frow) * 32 + kg * 8];
#pragma unroll
    for (int i = 0; i < 4; i++)
      fb[i] = *(const bf16x8*)&Bs[(wn + i * 16 + frow) * 32 + kg * 8];
#pragma unroll
    for (int i = 0; i < 4; i++)
#pragma unroll
      for (int j = 0; j < 4; j++)
        acc[i][j] = __builtin_amdgcn_mfma_f32_16x16x32_bf16(fa[i], fb[j], acc[i][j], 0, 0, 0);
    __syncthreads();
  }

  const int crow = (lane >> 4) * 4, ccol = lane & 15;
  if (MODE == 2) {
    float gate = 1.f / (1.f + __expf(-gatep[0]));
#pragma unroll
    for (int i = 0; i < 4; i++)
#pragma unroll
      for (int j = 0; j < 4; j++)
#pragma unroll
        for (int r = 0; r < 4; r++) {
          int gm = bm + wm + i * 16 + crow + r;
          int gn = bn + wn + j * 16 + ccol;
          size_t off = (size_t)gm * D_MODEL + gn;
          out_f[off] = xres[off] + gate * acc[i][j][r];
        }
  } else if (MODE == 0) {
#pragma unroll
    for (int i = 0; i < 4; i++)
#pragma unroll
      for (int j = 0; j < 4; j++)
#pragma unroll
        for (int r = 0; r < 4; r++) {
          int gm = bm + wm + i * 16 + crow + r;
          int gn = bn + wn + j * 16 + ccol;
          int b = gm >> 11, t = gm & 2047, h = gn >> 6, d = gn & 63;
          out_b[((((size_t)b * NH + h) * TT + t) << 6) + d] = f2bf(acc[i][j][r]);
        }
  } else {
#pragma unroll
    for (int i = 0; i < 4; i++)
#pragma unroll
      for (int j = 0; j < 4; j++)
#pragma unroll
        for (int r = 0; r < 4; r++) {
          int gm = bm + wm + i * 16 + crow + r;
          int gn = bn + wn + j * 16 + ccol;
          int b = gm >> 5, jj = gm & 31;
          if (gn < 1024) {
            int h = gn >> 6, d = gn & 63;
            out_f[((((size_t)b * NH + h) * KRET + jj) << 6) + d] = acc[i][j][r];
          } else {
            int gn2 = gn - 1024;
            int h = gn2 >> 6, d = gn2 & 63;
            out_f2[((((size_t)b * NH + h) * KRET + jj) << 6) + d] = acc[i][j][r];
          }
        }
  }
}

// ---------------- cross-attention over k=32 retrieved docs ----------------
__global__ __launch_bounds__(256) void k_attn(const unsigned short* __restrict__ Qb,
                                              const float* __restrict__ Kws,
                                              const float* __restrict__ Vws,
                                              unsigned short* __restrict__ ctx) {
  __shared__ __align__(16) float Ks[KRET * HD];
  __shared__ __align__(16) float Vs[KRET * HD];
  int bh = blockIdx.y; int b = bh >> 4, h = bh & 15;
  int tid = threadIdx.x;
  int t = blockIdx.x * 256 + tid;
  const float4* kp = (const float4*)(Kws + (size_t)bh * KRET * HD);
  const float4* vp = (const float4*)(Vws + (size_t)bh * KRET * HD);
  ((float4*)Ks)[tid] = kp[tid];
  ((float4*)Ks)[tid + 256] = kp[tid + 256];
  ((float4*)Vs)[tid] = vp[tid];
  ((float4*)Vs)[tid + 256] = vp[tid + 256];
  __syncthreads();

  const uint4* qp = (const uint4*)(Qb + ((size_t)bh * TT + t) * HD);
  float q[64];
#pragma unroll
  for (int i = 0; i < 8; i++) {
    uint4 u = qp[i];
    unsigned vals[4] = {u.x, u.y, u.z, u.w};
#pragma unroll
    for (int w = 0; w < 4; w++) {
      q[i * 8 + w * 2 + 0] = bf2f((unsigned short)(vals[w] & 0xffffu));
      q[i * 8 + w * 2 + 1] = bf2f((unsigned short)(vals[w] >> 16));
    }
  }
  float s[KRET];
#pragma unroll
  for (int j = 0; j < KRET; j++) {
    const float4* kr = (const float4*)&Ks[j * HD];
    float a = 0.f;
#pragma unroll
    for (int d4 = 0; d4 < 16; d4++) {
      float4 kk = kr[d4];
      a += q[d4 * 4 + 0] * kk.x + q[d4 * 4 + 1] * kk.y +
           q[d4 * 4 + 2] * kk.z + q[d4 * 4 + 3] * kk.w;
    }
    s[j] = a * 0.125f;
  }
  float m = s[0];
#pragma unroll
  for (int j = 1; j < KRET; j++) m = fmaxf(m, s[j]);
  float sum = 0.f;
#pragma unroll
  for (int j = 0; j < KRET; j++) { s[j] = __expf(s[j] - m); sum += s[j]; }
  float inv = 1.f / sum;
  float o[64];
#pragma unroll
  for (int d = 0; d < 64; d++) o[d] = 0.f;
#pragma unroll
  for (int j = 0; j < KRET; j++) {
    float p = s[j] * inv;
    const float4* vr = (const float4*)&Vs[j * HD];
#pragma unroll
    for (int d4 = 0; d4 < 16; d4++) {
      float4 vv = vr[d4];
      o[d4 * 4 + 0] += p * vv.x; o[d4 * 4 + 1] += p * vv.y;
      o[d4 * 4 + 2] += p * vv.z; o[d4 * 4 + 3] += p * vv.w;
    }
  }
  unsigned short* cp = ctx + ((size_t)(b * TT + t)) * D_MODEL + h * HD;
#pragma unroll
  for (int d4 = 0; d4 < 16; d4++) {
    ushort4 w4;
    w4.x = f2bf(o[d4 * 4 + 0]); w4.y = f2bf(o[d4 * 4 + 1]);
    w4.z = f2bf(o[d4 * 4 + 2]); w4.w = f2bf(o[d4 * 4 + 3]);
    ((ushort4*)cp)[d4] = w4;
  }
}

extern "C" void kernel_launch(void* const* d_in, const int* in_sizes, int n_in,
                              void* d_out, int out_size, void* d_ws, size_t ws_size,
                              hipStream_t stream) {
  const float* x = (const float*)d_in[0];
  const float* mk = (const float*)d_in[1];
  const float* mv = (const float*)d_in[2];
  const float* Wq = (const float*)d_in[3];
  const float* Wk = (const float*)d_in[4];
  const float* Wv = (const float*)d_in[5];
  const float* Wo = (const float*)d_in[6];
  const float* gatep = (const float*)d_in[7];
  float* out = (float*)d_out;

  char* ws = (char*)d_ws;
  unsigned short* xb   = (unsigned short*)(ws);               // 32MB x bf16; reused as ctx bf16
  unsigned short* Qb   = (unsigned short*)(ws + 33554432);    // 32MB Q bf16 (B,H,T,hd)
  unsigned short* WqT  = (unsigned short*)(ws + 67108864);    // 2MB
  unsigned short* WkvT = (unsigned short*)(ws + 69206016);    // 4MB (Wk^T then Wv^T)
  unsigned short* WoT  = (unsigned short*)(ws + 73400320);    // 2MB
  float* qpart = (float*)(ws + 75497472);                     // 256KB (dead after k_qnorm; reused below)
  float* cval  = (float*)(ws + 75497472);                     // 64KB  (reuses qpart region)
  int*   cidxb = (int*)(ws + 75497472 + 65536);               // 64KB
  float* qn    = (float*)(ws + 75759616);                     // 32KB
  float* sims  = (float*)(ws + 75792384);                     // 4MB
  int*   idx   = (int*)(ws + 79986688);                       // 1KB
  unsigned short* retr = (unsigned short*)(ws + 79987712);    // 512KB
  float* Kws   = (float*)(ws + 80512000);                     // 1MB (B,H,k,hd)
  float* Vws   = (float*)(ws + 81560576);                     // 1MB

  // 1. x -> bf16
  k_conv_bf16<<<dim3(16384), 256, 0, stream>>>(x, xb, MTOK * D_MODEL / 4);
  // 2. weight transposes -> bf16 B^T layouts
  k_transW<<<dim3(16, 16, 4), 256, 0, stream>>>(Wq, Wk, Wv, Wo,
                                                WqT, WkvT, WkvT + 1048576, WoT);
  // 3-4. mean-pool q then normalize
  k_meanpart<<<dim3(4, 8, 8), 256, 0, stream>>>(x, qpart);
  k_qnorm<<<dim3(8), 256, 0, stream>>>(qpart, qn);
  // 5. cosine sims vs key bank
  k_sims<<<dim3(BANK / 16), 256, 0, stream>>>(mk, qn, sims);
  // 6. two-stage exact top-32 per batch
  k_topk_local<<<dim3(64, 8), 256, 0, stream>>>(sims, cval, cidxb);
  k_topk_merge<<<dim3(8), 256, 0, stream>>>(cval, cidxb, idx);
  // 7. gather retrieved values -> bf16
  k_gather<<<dim3(256), 256, 0, stream>>>(mv, idx, retr);
  // 8. Q = x @ Wq  (writes (B,H,T,hd) bf16)
  k_gemm<0><<<dim3(128, 8), 256, 0, stream>>>(xb, WqT, nullptr, Qb, nullptr, nullptr, nullptr);
  // 9. K,V = retrieved @ [Wk;Wv]
  k_gemm<1><<<dim3(2, 16), 256, 0, stream>>>(retr, WkvT, Kws, nullptr, Vws, nullptr, nullptr);
  // 10. attention -> ctx bf16 (reuses xb)
  k_attn<<<dim3(8, 128), 256, 0, stream>>>(Qb, Kws, Vws, xb);
  // 11. out = x + sigmoid(gate) * ctx @ Wo
  k_gemm<2><<<dim3(128, 8), 256, 0, stream>>>(xb, WoT, out, nullptr, nullptr, x, gatep);
}